// Round 6
// baseline (1077.291 us; speedup 1.0000x reference)
//
#include <hip/hip_runtime.h>

#define Gn 4
#define Nn 50000
#define En 800000
#define Bq 32
#define F_IN 64
#define Hn 128
#define HEADS 8
#define HD 16
#define NNODES 50000
#define NB 196     // (Nn+255)/256
#define FCHUNK 4096
#define NCH ((En + FCHUNK - 1) / FCHUNK)  // 196 chunks per queue

using v8s = __attribute__((ext_vector_type(8))) short;
using v4f = __attribute__((ext_vector_type(4))) float;

// ---- bf16 helpers (RNE) ----
__device__ __forceinline__ float bf2f(unsigned short u) {
    unsigned int x = ((unsigned int)u) << 16;
    float f; __builtin_memcpy(&f, &x, 4); return f;
}
__device__ __forceinline__ unsigned short f2bf(float f) {
    unsigned int x; __builtin_memcpy(&x, &f, 4);
    x = (x + 0x7fffu + ((x >> 16) & 1u)) >> 16;
    return (unsigned short)x;
}
__device__ __forceinline__ unsigned int xcc_id() {
    unsigned int x;
    asm volatile("s_getreg_b32 %0, hwreg(HW_REG_XCC_ID)" : "=s"(x));
    return x & 7;
}

// ---------------- XCD-affine degree count: queue q = (g<<1)|half ----------------
// Each block drains its own XCD's queue via tickets, then steals. Scattered
// atomics land in a 100KB half-region touched by (mostly) one XCD -> L2-local.
__global__ __launch_bounds__(256) void k_degx(const int* __restrict__ ei, int* __restrict__ degi,
                                              int* __restrict__ tickets) {
    int myq = xcc_id();
    __shared__ int sT;
    for (int qi = 0; qi < 8; ++qi) {
        int q = (myq + qi) & 7;
        int g = q >> 1, half = q & 1;
        const int* col = ei + (size_t)g * 2 * En + En;
        int* degg = degi + g * Nn;
        while (true) {
            __syncthreads();
            if (threadIdx.x == 0) sT = atomicAdd(&tickets[q], 1);
            __syncthreads();
            int chunk = sT;
            if (chunk >= NCH) break;
            int emax = min((chunk + 1) * FCHUNK, En);
            for (int e = chunk * FCHUNK + threadIdx.x; e < emax; e += 256) {
                int c = col[e];
                if (((c >= Nn / 2) ? 1 : 0) == half) atomicAdd(&degg[c], 1);
            }
        }
    }
}

// ---------------- scan stage 1: per-block sums ----------------
__global__ __launch_bounds__(256) void k_bsum4(const int* __restrict__ degi, int* __restrict__ bsum) {
    __shared__ int red[4];
    int g = blockIdx.y;
    int i = blockIdx.x * 256 + threadIdx.x;
    int v = (i < Nn) ? degi[g * Nn + i] : 0;
#pragma unroll
    for (int off = 32; off > 0; off >>= 1) v += __shfl_down(v, off, 64);
    if ((threadIdx.x & 63) == 0) red[threadIdx.x >> 6] = v;
    __syncthreads();
    if (threadIdx.x == 0) bsum[g * 256 + blockIdx.x] = red[0] + red[1] + red[2] + red[3];
}

// ---------------- scan stage 2: exclusive scan of NB block sums per graph ----------------
__global__ __launch_bounds__(256) void k_bscan4(int* __restrict__ bsum) {
    __shared__ int s[256];
    int g = blockIdx.x, t = threadIdx.x;
    int v = (t < NB) ? bsum[g * 256 + t] : 0;
    s[t] = v;
    __syncthreads();
    for (int d = 1; d < 256; d <<= 1) {
        int u = (t >= d) ? s[t - d] : 0;
        __syncthreads();
        s[t] += u;
        __syncthreads();
    }
    if (t < NB) bsum[g * 256 + t] = (t > 0) ? s[t - 1] : 0;
}

// ---------------- scan stage 3: offsets + cursors + dinv ----------------
__global__ __launch_bounds__(256) void k_off4(const int* __restrict__ degi, const int* __restrict__ bbase,
                                              int* __restrict__ off, int* __restrict__ cur,
                                              float* __restrict__ dinv) {
    __shared__ int s[256];
    int g = blockIdx.y, b = blockIdx.x, t = threadIdx.x;
    int i = b * 256 + t;
    int d = (i < Nn) ? degi[g * Nn + i] : 0;
    s[t] = d;
    __syncthreads();
    for (int dd = 1; dd < 256; dd <<= 1) {
        int u = (t >= dd) ? s[t - dd] : 0;
        __syncthreads();
        s[t] += u;
        __syncthreads();
    }
    if (i < Nn) {
        int base = bbase[g * 256 + b];
        off[g * (Nn + 1) + i] = base + s[t] - d;
        cur[g * Nn + i] = 0;
        dinv[g * Nn + i] = rsqrtf((float)d + 1.0f);
        if (i == Nn - 1) off[g * (Nn + 1) + Nn] = base + s[t];
    }
}

// ---------------- XCD-affine CSR fill: same queue structure as k_degx ----------------
__global__ __launch_bounds__(256) void k_fillx(const int* __restrict__ ei, const int* __restrict__ off,
                                               int* __restrict__ cur, unsigned short* __restrict__ srcs,
                                               int* __restrict__ tickets) {
    int myq = xcc_id();
    __shared__ int sT;
    for (int qi = 0; qi < 8; ++qi) {
        int q = (myq + qi) & 7;
        int g = q >> 1, half = q & 1;
        const int* row = ei + (size_t)g * 2 * En;
        const int* col = row + En;
        const int* offg = off + g * (Nn + 1);
        int* curg = cur + g * Nn;
        unsigned short* sg = srcs + (size_t)g * En;
        while (true) {
            __syncthreads();
            if (threadIdx.x == 0) sT = atomicAdd(&tickets[q], 1);
            __syncthreads();
            int chunk = sT;
            if (chunk >= NCH) break;
            int emax = min((chunk + 1) * FCHUNK, En);
            for (int e = chunk * FCHUNK + threadIdx.x; e < emax; e += 256) {
                int c = col[e];
                if (((c >= Nn / 2) ? 1 : 0) == half) {
                    int pos = offg[c] + atomicAdd(&curg[c], 1);
                    sg[pos] = (unsigned short)row[e];
                }
            }
        }
    }
}

// ---------------- cast + pre-scale: xbs = bf16(x * dinv) ----------------
__global__ __launch_bounds__(256) void k_cast(const float* __restrict__ x, const float* __restrict__ dinv,
                                              unsigned short* __restrict__ xbs) {
    int i = blockIdx.x * 256 + threadIdx.x;  // one float4 per thread, N*16 total
    if (i >= Nn * 16) return;
    float dc = dinv[i >> 4];
    float4 v = *(const float4*)&x[i * 4];
    ushort4 u = make_ushort4(f2bf(v.x * dc), f2bf(v.y * dc), f2bf(v.z * dc), f2bf(v.w * dc));
    *(ushort4*)&xbs[i * 4] = u;
}

// ---------------- agg 64-feat: z1 = dinv_c * (sum_e xs_r + xs_c) ----------------
__global__ __launch_bounds__(256) void k_agg1(const unsigned short* __restrict__ xs, const int* __restrict__ off,
                                              const unsigned short* __restrict__ srcs,
                                              const float* __restrict__ dinv, unsigned short* __restrict__ z1) {
    int node = blockIdx.x * 8 + (threadIdx.x >> 5);
    int lane = threadIdx.x & 31;
    int f2 = lane << 1;
    int beg = off[node], end = off[node + 1];
    ushort2 own = *(const ushort2*)&xs[(long)node * 64 + f2];
    float ax = bf2f(own.x), ay = bf2f(own.y);
    for (int e = beg; e < end; e += 32) {
        int k = min(32, end - e);
        int sid = 0;
        if (lane < k) sid = srcs[e + lane];
        for (int j = 0; j < k; ++j) {
            int s = __shfl(sid, j, 32);
            ushort2 u = *(const ushort2*)&xs[(long)s * 64 + f2];
            ax += bf2f(u.x);
            ay += bf2f(u.y);
        }
    }
    float dc = dinv[node];
    *(ushort2*)&z1[(long)node * 64 + f2] = make_ushort2(f2bf(ax * dc), f2bf(ay * dc));
}

// ---------------- agg 128-feat: z2 = dinv_c * (sum_e y1s_r + y1s_c) ----------------
__global__ __launch_bounds__(256) void k_agg2(const unsigned short* __restrict__ h, const int* __restrict__ off,
                                              const unsigned short* __restrict__ srcs,
                                              const float* __restrict__ dinv, unsigned short* __restrict__ z2) {
    int node = blockIdx.x * 8 + (threadIdx.x >> 5);
    int lane = threadIdx.x & 31;
    int f4 = lane << 2;
    int beg = off[node], end = off[node + 1];
    ushort4 own = *(const ushort4*)&h[(long)node * 128 + f4];
    float a0 = bf2f(own.x), a1 = bf2f(own.y), a2 = bf2f(own.z), a3 = bf2f(own.w);
    for (int e = beg; e < end; e += 32) {
        int k = min(32, end - e);
        int sid = 0;
        if (lane < k) sid = srcs[e + lane];
        for (int j = 0; j < k; ++j) {
            int s = __shfl(sid, j, 32);
            ushort4 u = *(const ushort4*)&h[(long)s * 128 + f4];
            a0 += bf2f(u.x);
            a1 += bf2f(u.y);
            a2 += bf2f(u.z);
            a3 += bf2f(u.w);
        }
    }
    float dc = dinv[node];
    *(ushort4*)&z2[(long)node * 128 + f4] =
        make_ushort4(f2bf(a0 * dc), f2bf(a1 * dc), f2bf(a2 * dc), f2bf(a3 * dc));
}

// ---------------- MFMA mm: out_bf16 = relu(zin[N,K]bf16 @ W[K,128]f32 + b) [* dinv if SCALE] ----------------
template <int K, bool SCALE>
__global__ __launch_bounds__(256) void k_mmfma(const unsigned short* __restrict__ zin,
                                               const float* __restrict__ W, const float* __restrict__ bias,
                                               const float* __restrict__ dinv,
                                               unsigned short* __restrict__ outp, int nrows) {
    __shared__ __align__(16) unsigned short Wt[128 * (K + 8)];  // W transposed [n][k], bf16, +8 pad
    __shared__ __align__(16) unsigned short At[32 * (K + 8)];   // A rows [r][k], bf16
    int t = threadIdx.x;
    int base = blockIdx.x * 32;

#pragma unroll
    for (int i = 0; i < K * 128 / 256; ++i) {
        int idx = i * 256 + t;
        int k = idx >> 7, n = idx & 127;
        Wt[n * (K + 8) + k] = f2bf(W[idx]);
    }
    {
        int r = t >> 3, cb = (t & 7) * (K / 8);
        long grow = base + r;
#pragma unroll
        for (int j = 0; j < K / 32; ++j) {
            ushort4 u = make_ushort4(0, 0, 0, 0);
            if (grow < nrows) u = *(const ushort4*)&zin[grow * K + cb + j * 4];
            *(ushort4*)&At[r * (K + 8) + cb + j * 4] = u;
        }
    }
    __syncthreads();

    int w = t >> 6, lane = t & 63;
    int wm = w & 1, wn = w >> 1;
    int m = lane & 15, q = lane >> 4;
    v4f acc[4] = {};
    const unsigned short* Ap = &At[(wm * 16 + m) * (K + 8) + q * 8];
    const unsigned short* Bp = &Wt[(wn * 64 + m) * (K + 8) + q * 8];
    const int rstep = 16 * (K + 8);
#pragma unroll
    for (int ks = 0; ks < K / 32; ++ks) {
        v8s a = *(const v8s*)(Ap + ks * 32);
        v8s b0 = *(const v8s*)(Bp + 0 * rstep + ks * 32);
        v8s b1 = *(const v8s*)(Bp + 1 * rstep + ks * 32);
        v8s b2 = *(const v8s*)(Bp + 2 * rstep + ks * 32);
        v8s b3 = *(const v8s*)(Bp + 3 * rstep + ks * 32);
        acc[0] = __builtin_amdgcn_mfma_f32_16x16x32_bf16(a, b0, acc[0], 0, 0, 0);
        acc[1] = __builtin_amdgcn_mfma_f32_16x16x32_bf16(a, b1, acc[1], 0, 0, 0);
        acc[2] = __builtin_amdgcn_mfma_f32_16x16x32_bf16(a, b2, acc[2], 0, 0, 0);
        acc[3] = __builtin_amdgcn_mfma_f32_16x16x32_bf16(a, b3, acc[3], 0, 0, 0);
    }

    int col0 = wn * 64 + m;
    int rbase = base + wm * 16 + q * 4;
    float dv[4];
#pragma unroll
    for (int rg = 0; rg < 4; ++rg)
        dv[rg] = SCALE ? ((rbase + rg < nrows) ? dinv[rbase + rg] : 1.f) : 1.f;
#pragma unroll
    for (int nt = 0; nt < 4; ++nt) {
        float bc = bias[col0 + nt * 16];
#pragma unroll
        for (int rg = 0; rg < 4; ++rg) {
            int row = rbase + rg;
            if (row < nrows) {
                float o = fmaxf(acc[nt][rg] + bc, 0.f);
                outp[(long)row * 128 + col0 + nt * 16] = f2bf(o * dv[rg]);
            }
        }
    }
}

// ---------------- segment mean pool (batch sorted), bf16 input ----------------
__global__ __launch_bounds__(128) void k_pool(const unsigned short* __restrict__ y, const int* __restrict__ batch,
                                              float* __restrict__ emb_sum, float* __restrict__ cnt, int g) {
    int f = threadIdx.x;  // 128
    int start = blockIdx.x * 64;
    int end = min(start + 64, Nn);
    if (start >= Nn) return;
    float acc = 0.f;
    int cacc = 0;
    int cur = batch[start];
    for (int i = start; i < end; ++i) {
        int b = batch[i];
        if (b != cur) {
            atomicAdd(&emb_sum[(g * Bq + cur) * Hn + f], acc);
            if (f == 0) atomicAdd(&cnt[g * Bq + cur], (float)cacc);
            acc = 0.f; cacc = 0; cur = b;
        }
        acc += bf2f(y[(long)i * Hn + f]);
        cacc++;
    }
    atomicAdd(&emb_sum[(g * Bq + cur) * Hn + f], acc);
    if (f == 0) atomicAdd(&cnt[g * Bq + cur], (float)cacc);
}

// ---------------- whole MHA: one block per batch element b ----------------
__global__ __launch_bounds__(128) void k_attn(const float* __restrict__ emb_sum, const float* __restrict__ cnt,
                                              const float* __restrict__ ipw, const float* __restrict__ ipb,
                                              const float* __restrict__ opw, const float* __restrict__ opb,
                                              float* __restrict__ pooled) {
    int b = blockIdx.x;
    int f = threadIdx.x;  // 128
    __shared__ float es[4][128], qs[4][128], ks[4][128], vs[4][128], sc[128], cx[4][128];
#pragma unroll
    for (int g = 0; g < 4; ++g) {
        float c = cnt[g * Bq + b];
        es[g][f] = (c > 0.f) ? emb_sum[(g * Bq + b) * Hn + f] / c : 0.f;
    }
    __syncthreads();
#pragma unroll
    for (int g = 0; g < 4; ++g) {
        float q = ipb[f], k = ipb[Hn + f], v = ipb[2 * Hn + f];
        for (int j = 0; j < Hn; ++j) {
            float e = es[g][j];
            q += e * ipw[f * Hn + j];
            k += e * ipw[(Hn + f) * Hn + j];
            v += e * ipw[(2 * Hn + f) * Hn + j];
        }
        qs[g][f] = q; ks[g][f] = k; vs[g][f] = v;
    }
    __syncthreads();
    {
        int h = f >> 4, g = (f >> 2) & 3, kk = f & 3;
        float s = 0.f;
        for (int d = 0; d < 16; ++d) s += qs[g][h * 16 + d] * ks[kk][h * 16 + d];
        sc[f] = s * 0.25f;
    }
    __syncthreads();
    {
        int h = f >> 4;
#pragma unroll
        for (int g = 0; g < 4; ++g) {
            int bi = h * 16 + g * 4;
            float s0 = sc[bi], s1 = sc[bi + 1], s2 = sc[bi + 2], s3 = sc[bi + 3];
            float m = fmaxf(fmaxf(s0, s1), fmaxf(s2, s3));
            float e0 = __expf(s0 - m), e1 = __expf(s1 - m), e2 = __expf(s2 - m), e3 = __expf(s3 - m);
            float rinv = 1.f / (e0 + e1 + e2 + e3);
            cx[g][f] = (e0 * vs[0][f] + e1 * vs[1][f] + e2 * vs[2][f] + e3 * vs[3][f]) * rinv;
        }
    }
    __syncthreads();
#pragma unroll
    for (int g = 0; g < 4; ++g) {
        float a = opb[f];
        for (int j = 0; j < Hn; ++j) a += cx[g][j] * opw[f * Hn + j];
        atomicAdd(&pooled[g * Hn + f], a * (1.0f / Bq));
    }
}

// ---------------- final: out[g,n] = (pooled[g] . lin_w[n] + lin_b[n]) * 60 + 50 ----------------
__global__ __launch_bounds__(256) void k_final(const float* __restrict__ pooled, const float* __restrict__ lw,
                                               const float* __restrict__ lb, float* __restrict__ out) {
    __shared__ float ps[512];
    int t = threadIdx.x;
    ps[t] = pooled[t];
    ps[t + 256] = pooled[t + 256];
    __syncthreads();
    int wave = t >> 6, lane = t & 63;
    int n = blockIdx.x * 4 + wave;
    if (n >= NNODES) return;
    float2 w = *(const float2*)&lw[(long)n * 128 + lane * 2];
    float a0 = w.x * ps[0 * 128 + lane * 2] + w.y * ps[0 * 128 + lane * 2 + 1];
    float a1 = w.x * ps[1 * 128 + lane * 2] + w.y * ps[1 * 128 + lane * 2 + 1];
    float a2 = w.x * ps[2 * 128 + lane * 2] + w.y * ps[2 * 128 + lane * 2 + 1];
    float a3 = w.x * ps[3 * 128 + lane * 2] + w.y * ps[3 * 128 + lane * 2 + 1];
#pragma unroll
    for (int off = 32; off > 0; off >>= 1) {
        a0 += __shfl_down(a0, off);
        a1 += __shfl_down(a1, off);
        a2 += __shfl_down(a2, off);
        a3 += __shfl_down(a3, off);
    }
    if (lane == 0) {
        float bn = lb[n];
        out[0 * NNODES + n] = (a0 + bn) * 60.f + 50.f;
        out[1 * NNODES + n] = (a1 + bn) * 60.f + 50.f;
        out[2 * NNODES + n] = (a2 + bn) * 60.f + 50.f;
        out[3 * NNODES + n] = (a3 + bn) * 60.f + 50.f;
    }
}

extern "C" void kernel_launch(void* const* d_in, const int* in_sizes, int n_in,
                              void* d_out, int out_size, void* d_ws, size_t ws_size,
                              hipStream_t stream) {
    const float* x   = (const float*)d_in[0];
    const int*   ei  = (const int*)d_in[1];
    const int*   bat = (const int*)d_in[2];
    const float* W1  = (const float*)d_in[3];
    const float* b1  = (const float*)d_in[4];
    const float* W2  = (const float*)d_in[5];
    const float* b2  = (const float*)d_in[6];
    const float* ipw = (const float*)d_in[7];
    const float* ipb = (const float*)d_in[8];
    const float* opw = (const float*)d_in[9];
    const float* opb = (const float*)d_in[10];
    const float* lw  = (const float*)d_in[11];
    const float* lb  = (const float*)d_in[12];
    float* out = (float*)d_out;

    // workspace carve-up (~61 MB)
    char* p = (char*)d_ws;
    unsigned short* xbs = (unsigned short*)p;                // [N,64]  bf16    6.4 MB
    unsigned short* z1  = xbs + (size_t)Nn * 64;             // [N,64]  bf16    6.4 MB
    unsigned short* y1b = (unsigned short*)(p + 12800000);   // [N,128] bf16   12.8 MB
    unsigned short* z2  = (unsigned short*)(p + 25600000);   // [N,128] bf16   12.8 MB
    unsigned short* y2b = (unsigned short*)(p + 38400000);   // [N,128] bf16   12.8 MB
    int*   degi = (int*)(p + 51200000);                      // [4][N]
    int*   off  = degi + 4 * Nn;                             // [4][N+1]
    int*   cur  = off + 4 * (Nn + 1);                        // [4][N]
    float* dinv = (float*)(cur + 4 * Nn);                    // [4][N]
    int*   bsum = (int*)(dinv + 4 * Nn);                     // [4][256]
    int*   tickets = bsum + 4 * 256;                         // [16]: 8 deg + 8 fill
    unsigned short* srcs = (unsigned short*)(tickets + 16);  // [4][E] ushort
    float* emb    = (float*)(srcs + (size_t)4 * En);         // [G,B,H]
    float* cnt    = emb + Gn * Bq * Hn;                      // [G,B]
    float* pooled = cnt + Gn * Bq;                           // [G,H]

    hipMemsetAsync(degi, 0, 4 * Nn * sizeof(int), stream);
    hipMemsetAsync(tickets, 0, 16 * sizeof(int), stream);
    hipMemsetAsync(emb, 0, Gn * Bq * Hn * sizeof(float), stream);
    hipMemsetAsync(cnt, 0, Gn * Bq * sizeof(float), stream);
    hipMemsetAsync(pooled, 0, Gn * Hn * sizeof(float), stream);

    const int agGrid = (Nn + 7) / 8;                 // 6250
    const int mmGrid = (Nn + 31) / 32;               // 1563
    const int plGrid = (Nn + 63) / 64;               // 782
    const int ctGrid = (Nn * 16 + 255) / 256;        // 3125

    // CSR prep: XCD-affine degree + scan + XCD-affine fill
    k_degx<<<1024, 256, 0, stream>>>(ei, degi, tickets);
    k_bsum4<<<dim3(NB, 4), 256, 0, stream>>>(degi, bsum);
    k_bscan4<<<4, 256, 0, stream>>>(bsum);
    k_off4<<<dim3(NB, 4), 256, 0, stream>>>(degi, bsum, off, cur, dinv);
    k_fillx<<<1024, 256, 0, stream>>>(ei, off, cur, srcs, tickets + 8);

    for (int g = 0; g < Gn; ++g) {
        const float* xg = x + (size_t)g * Nn * F_IN;
        const int* bg = bat + (size_t)g * Nn;
        const int* offg = off + g * (Nn + 1);
        const float* dinvg = dinv + g * Nn;
        const unsigned short* srcg = srcs + (size_t)g * En;

        k_cast<<<ctGrid, 256, 0, stream>>>(xg, dinvg, xbs);

        // layer 1: z1 = dinv*(sum xs + xs_self); y1s = relu(z1@W1+b1)*dinv
        k_agg1<<<agGrid, 256, 0, stream>>>(xbs, offg, srcg, dinvg, z1);
        k_mmfma<64, true><<<mmGrid, 256, 0, stream>>>(z1, W1, b1, dinvg, y1b, Nn);

        // layer 2: z2 = dinv*(sum y1s + y1s_self); y2 = relu(z2@W2+b2)
        k_agg2<<<agGrid, 256, 0, stream>>>(y1b, offg, srcg, dinvg, z2);
        k_mmfma<128, false><<<mmGrid, 256, 0, stream>>>(z2, W2, b2, dinvg, y2b, Nn);

        // pool
        k_pool<<<plGrid, 128, 0, stream>>>(y2b, bg, emb, cnt, g);
    }

    k_attn<<<Bq, 128, 0, stream>>>(emb, cnt, ipw, ipb, opw, opb, pooled);
    k_final<<<(NNODES + 3) / 4, 256, 0, stream>>>(pooled, lw, lb, out);
}